// Round 15
// baseline (1558.422 us; speedup 1.0000x reference)
//
#include <hip/hip_runtime.h>
#include <math.h>

#define BB 4
#define NF 128
#define CS 192
#define CH 96
#define H1 64
#define W1 64
#define H2 128
#define W2 128
#define P1 (H1*W1)
#define P2 (H2*W2)
#define EPSV 1e-5f
#define DTV 0.25f
#define NSLICE 32
#define SLOTSZ (1536 * NSLICE)

typedef __attribute__((ext_vector_type(8))) short short8;
typedef __attribute__((ext_vector_type(4))) float f32x4;

__device__ __forceinline__ float softplus_f(float x) {
    return fmaxf(x, 0.0f) + __logf(1.0f + __expf(-fabsf(x)));
}
__device__ __forceinline__ unsigned f2bf(float f) {
    unsigned u = __float_as_uint(f);
    return (u + 0x7FFFu + ((u >> 16) & 1u)) >> 16;   // RNE to bf16
}
__device__ __forceinline__ float bf2f(short s) {
    return __uint_as_float(((unsigned)(unsigned short)s) << 16);
}
__device__ __forceinline__ int packbf(float a, float b) {
    return (int)(f2bf(a) | (f2bf(b) << 16));
}

__global__ __launch_bounds__(256) void zero_kernel(float* __restrict__ p, int n) {
    int i = blockIdx.x * 256 + threadIdx.x;
    if (i < n) p[i] = 0.f;
}

// per-(b,c) raw (sum,sumsq) over HW for fp32 NCHW input x. grid = B*C.
__global__ __launch_bounds__(256) void meanvar_raw_kernel(const float* __restrict__ x,
                                                          float* __restrict__ mv, int HW) {
    int bc = blockIdx.x;
    const float* p = x + (size_t)bc * HW;
    float s = 0.f, s2 = 0.f;
    for (int i = threadIdx.x; i < HW; i += 256) {
        float v = p[i];
        s += v; s2 += v * v;
    }
    __shared__ float sh[512];
    sh[threadIdx.x] = s; sh[256 + threadIdx.x] = s2;
    __syncthreads();
    for (int o = 128; o > 0; o >>= 1) {
        if (threadIdx.x < o) {
            sh[threadIdx.x] += sh[threadIdx.x + o];
            sh[256 + threadIdx.x] += sh[256 + threadIdx.x + o];
        }
        __syncthreads();
    }
    if (threadIdx.x == 0) {
        mv[2 * bc]     = sh[0];
        mv[2 * bc + 1] = sh[256];
    }
}

// repack w[co][ci][3][3] fp32 -> MFMA-fragment-linear bf16, CHUNK-CONTIGUOUS:
// chunk c = it*9 + tap; WQF[(c*COG + cog)*64 + lane][8], lane = q*16 + lx,
// holding w[co = cog*16+lx][ci = it*32 + q*8 + e].
__global__ __launch_bounds__(256) void repack_w_kernel(const float* __restrict__ w,
                                                       short* __restrict__ wq,
                                                       int Cout, int Cin) {
    int idx = blockIdx.x * 256 + threadIdx.x;
    int total = Cout * Cin * 9;
    if (idx >= total) return;
    int tap = idx % 9;
    int t = idx / 9;
    int ci = t % Cin, co = t / Cin;
    int COGl = Cout >> 4;
    int cog = co >> 4, lx = co & 15;
    int it = ci >> 5, q = (ci >> 3) & 3, e = ci & 7;
    size_t o = (((size_t)(it * 9 + tap) * COGl + cog) * 64 + q * 16 + lx) * 8 + e;
    wq[o] = (short)f2bf(w[idx]);
}

// repack 1x1 w[co][ci] fp32 -> fragment-linear bf16.
__global__ __launch_bounds__(256) void repack_w1_kernel(const float* __restrict__ w,
                                                        short* __restrict__ wq,
                                                        int Cout, int Cin) {
    int idx = blockIdx.x * 256 + threadIdx.x;
    if (idx >= Cout * Cin) return;
    int ci = idx % Cin, co = idx / Cin;
    int COGl = Cout >> 4;
    int cog = co >> 4, lx = co & 15;
    int it = ci >> 5, q = (ci >> 3) & 3, e = ci & 7;
    size_t o = (((size_t)it * COGl + cog) * 64 + q * 16 + lx) * 8 + e;
    wq[o] = (short)f2bf(w[idx]);
}

// x fp32 NCHW (B,128,P1) -> bf16 NHWC [b][px][128], LDS transpose. grid (P1/64, B).
__global__ __launch_bounds__(256) void xcvt_kernel(const float* __restrict__ x,
                                                   short* __restrict__ xbf) {
    __shared__ int buf[64 * 68];
    const int tid = threadIdx.x;
    const int px = tid & 63, jj = tid >> 6;
    const int px0 = blockIdx.x * 64;
    const int b = blockIdx.y;
#pragma unroll
    for (int ji = 0; ji < 16; ji++) {
        int j = jj + 4 * ji;
        int c = 2 * j;
        float a = x[((size_t)(b * NF + c)) * P1 + px0 + px];
        float d = x[((size_t)(b * NF + c + 1)) * P1 + px0 + px];
        buf[px * 68 + j] = packbf(a, d);
    }
    __syncthreads();
#pragma unroll
    for (int k = 0; k < 4; k++) {
        int idx = tid + 256 * k;
        int p2 = idx >> 4, w4 = idx & 15;
        int4 v = *(const int4*)&buf[p2 * 68 + w4 * 4];
        *(int4*)(xbf + ((size_t)b * P1 + px0 + p2) * NF + w4 * 8) = v;
    }
}

// 3x3 SAME conv: whole input tile staged to LDS once, fully-unrolled chunk
// loop with DUAL triple-buffered prefetch (weights dist-2 global, bfr dist-1
// LDS). Outputs: OUTBF -> bf16 NHWC (LDS transpose); GOUT -> bf16 NCHW
// (G stage buffers, halves RK4 elementwise traffic); else fp32 NCHW.
// 256 threads = 4 waves: wave (wy,wc) owns 4 rows, co-half wc.
// grid (W/16, H/8, B*coblk), block 256.
template<int CIN, int NCG, bool OUTBF, bool GOUT, bool SUMS>
__global__ __launch_bounds__(256) void conv3x3_mfma(
    const short* __restrict__ in, const float* __restrict__ mvsums,
    const short* __restrict__ wq, const float* __restrict__ bias,
    float* __restrict__ outf, short* __restrict__ outbf, float* __restrict__ osum,
    int CoutT, int H, int W, int outC, int outCoff, int coblk)
{
    constexpr int ROWS = CIN + 8;            // shorts per px row
    constexpr int STGI = 180 * ROWS / 2;     // staging ints
    constexpr int SMEMI = (OUTBF && 128 * 52 > STGI) ? 128 * 52 : STGI;
    constexpr int NCGH = NCG / 2;
    __shared__ int smem[SMEMI];
    short* xt = (short*)smem;
    __shared__ float mvm[CIN], mvr[CIN];
    __shared__ float shs[2 * CH];
    const int tid = threadIdx.x;
    const int w4 = tid >> 6, lane = tid & 63;
    const int wy = w4 & 1, wc = w4 >> 1;
    const int lx = lane & 15, q = lane >> 4;
    const int x0 = blockIdx.x * 16, y0 = blockIdx.y * 8;
    const int b = blockIdx.z / coblk;
    const int co_base = (blockIdx.z % coblk) * (NCG * 16);
    const int slice = (blockIdx.x + (blockIdx.y << 3)) & (NSLICE - 1);
    const int HWp = H * W;
    const short* inb = in + (size_t)b * HWp * CIN;

    const float invHW = 1.0f / (float)HWp;
    for (int c = tid; c < CIN; c += 256) {
        float s = 0.f, s2 = 0.f;
#pragma unroll
        for (int sl = 0; sl < NSLICE; sl++) {
            s  += mvsums[(size_t)sl * 1536 + (b * CIN + c) * 2];
            s2 += mvsums[(size_t)sl * 1536 + (b * CIN + c) * 2 + 1];
        }
        float m  = s * invHW;
        float var = fmaxf(s2 * invHW - m * m, 0.f);
        mvm[c] = m;
        mvr[c] = rsqrtf(var + EPSV);
    }
    if (SUMS) for (int c = tid; c < 2 * CH; c += 256) shs[c] = 0.f;
    __syncthreads();

    // ---- stage the whole normalized tile (one pass, coalesced) ----
    constexpr int PARTS = CIN / 8;
    constexpr int TOT = 180 * PARTS;
    constexpr int NJ = (TOT + 255) / 256;
#pragma unroll
    for (int k = 0; k < NJ; k++) {
        int j = tid + 256 * k;
        if (j < TOT) {
            int px = j / PARTS, part = j - px * PARTS;
            int yy = px / 18, xx = px - yy * 18;
            int gy = y0 + yy - 1, gx = x0 + xx - 1;
            int4 wv = make_int4(0, 0, 0, 0);
            if (gy >= 0 && gy < H && gx >= 0 && gx < W) {
                int cb = part * 8;
                short8 v = *(const short8*)(inb + (size_t)(gy * W + gx) * CIN + cb);
                float4 m0 = *(const float4*)&mvm[cb];
                float4 m1 = *(const float4*)&mvm[cb + 4];
                float4 r0 = *(const float4*)&mvr[cb];
                float4 r1 = *(const float4*)&mvr[cb + 4];
                wv.x = packbf((bf2f(v[0]) - m0.x) * r0.x, (bf2f(v[1]) - m0.y) * r0.y);
                wv.y = packbf((bf2f(v[2]) - m0.z) * r0.z, (bf2f(v[3]) - m0.w) * r0.w);
                wv.z = packbf((bf2f(v[4]) - m1.x) * r1.x, (bf2f(v[5]) - m1.y) * r1.y);
                wv.w = packbf((bf2f(v[6]) - m1.z) * r1.z, (bf2f(v[7]) - m1.w) * r1.w);
            }
            *(int4*)(&xt[px * ROWS + part * 8]) = wv;
        }
    }
    __syncthreads();

    // ---- fully-unrolled dual-pipelined compute ----
    f32x4 acc[4][NCGH];
#pragma unroll
    for (int rr = 0; rr < 4; rr++)
#pragma unroll
        for (int cg = 0; cg < NCGH; cg++) acc[rr][cg] = (f32x4)(0.f);

    constexpr int NIT = CIN / 32;
    constexpr int NC = 9 * NIT;              // NC % 3 == 0 always
    const int COGl = CoutT >> 4;
    const short* wbase = wq + ((size_t)((co_base >> 4) + wc * NCGH) * 64 + lane) * 8;
    const size_t wstep = (size_t)COGl * 512;   // shorts per chunk

    auto ldw = [&](int c, short8* dst) {
#pragma unroll
        for (int cg = 0; cg < NCGH; cg++)
            dst[cg] = *(const short8*)(wbase + (size_t)c * wstep + (size_t)cg * 512);
    };
    auto ldb = [&](int c, short8* dst) {
        const int it = c / 9, tap = c - 9 * (c / 9);
        const int dy = tap / 3, dx = tap - 3 * (tap / 3);
#pragma unroll
        for (int rr = 0; rr < 4; rr++)
            dst[rr] = *(const short8*)(
                &xt[((wy * 4 + rr + dy) * 18 + lx + dx) * ROWS + it * 32 + q * 8]);
    };
    auto fma = [&](const short8* a, const short8* bfr) {
#pragma unroll
        for (int rr = 0; rr < 4; rr++)
#pragma unroll
            for (int cg = 0; cg < NCGH; cg++)
                acc[rr][cg] = __builtin_amdgcn_mfma_f32_16x16x32_bf16(
                    a[cg], bfr[rr], acc[rr][cg], 0, 0, 0);
    };

    short8 aA[NCGH], aB[NCGH], aC[NCGH];
    short8 bA[4], bB[4], bC[4];
    ldw(0, aA);
    ldw(1, aB);
    ldb(0, bA);
#pragma unroll
    for (int c = 0; c < NC; c += 3) {
        if (c + 2 < NC) ldw(c + 2, aC);
        if (c + 1 < NC) ldb(c + 1, bB);
        fma(aA, bA);
        if (c + 3 < NC) ldw(c + 3, aA);
        if (c + 2 < NC) ldb(c + 2, bC);
        if (c + 1 < NC) fma(aB, bB);
        if (c + 4 < NC) ldw(c + 4, aB);
        if (c + 3 < NC) ldb(c + 3, bA);
        if (c + 2 < NC) fma(aC, bC);
    }

    if (OUTBF) __syncthreads();   // xt reads done; smem reused as transpose buf

    float s1l[NCGH][4], s2l[NCGH][4];
    if (SUMS) {
#pragma unroll
        for (int cg = 0; cg < NCGH; cg++)
#pragma unroll
            for (int r = 0; r < 4; r++) { s1l[cg][r] = 0.f; s2l[cg][r] = 0.f; }
    }
#pragma unroll
    for (int rr = 0; rr < 4; rr++) {
        int y = y0 + wy * 4 + rr;
#pragma unroll
        for (int cg = 0; cg < NCGH; cg++) {
            float v[4];
#pragma unroll
            for (int r = 0; r < 4; r++) {
                int co = wc * (NCGH * 16) + cg * 16 + q * 4 + r;
                v[r] = softplus_f(acc[rr][cg][r] + bias[co_base + co]);
                if (SUMS) { s1l[cg][r] += v[r]; s2l[cg][r] += v[r] * v[r]; }
            }
            if (OUTBF) {
                int pl = (wy * 4 + rr) * 16 + lx;
                smem[pl * 52 + wc * (NCGH * 8) + cg * 8 + q * 2]     = packbf(v[0], v[1]);
                smem[pl * 52 + wc * (NCGH * 8) + cg * 8 + q * 2 + 1] = packbf(v[2], v[3]);
            } else if (GOUT) {
                short* ob = outbf + ((size_t)b * outC + outCoff + co_base) * HWp
                            + y * W + x0 + lx;
#pragma unroll
                for (int r = 0; r < 4; r++)
                    ob[(size_t)(wc * (NCGH * 16) + cg * 16 + q * 4 + r) * HWp] =
                        (short)f2bf(v[r]);
            } else {
                float* ob = outf + ((size_t)b * outC + outCoff + co_base) * HWp
                            + y * W + x0 + lx;
#pragma unroll
                for (int r = 0; r < 4; r++)
                    ob[(size_t)(wc * (NCGH * 16) + cg * 16 + q * 4 + r) * HWp] = v[r];
            }
        }
    }
    if (OUTBF) {
        __syncthreads();
#pragma unroll
        for (int k = 0; k < 6; k++) {
            int idx = tid + 256 * k;           // 1536 int4s: 128 px x 12 int4
            int pl2 = idx / 12, w4i = idx % 12;
            int4 v = *(const int4*)&smem[pl2 * 52 + w4i * 4];
            int pix = (y0 + (pl2 >> 4)) * W + x0 + (pl2 & 15);
            *(int4*)(outbf + ((size_t)b * HWp + pix) * 96 + w4i * 8) = v;
        }
    }
    if (SUMS) {
#pragma unroll
        for (int cg = 0; cg < NCGH; cg++)
#pragma unroll
            for (int r = 0; r < 4; r++) {
                float a1 = s1l[cg][r], a2 = s2l[cg][r];
#pragma unroll
                for (int mask = 1; mask < 16; mask <<= 1) {
                    a1 += __shfl_xor(a1, mask);
                    a2 += __shfl_xor(a2, mask);
                }
                if (lx == 0) {
                    int co = wc * (NCGH * 16) + cg * 16 + q * 4 + r;
                    atomicAdd(&shs[2 * co], a1);
                    atomicAdd(&shs[2 * co + 1], a2);
                }
            }
        __syncthreads();
        for (int c = tid; c < 2 * NCG * 16; c += 256)
            atomicAdd(&osum[(size_t)slice * 1536 + (size_t)b * 2 * NCG * 16 + c], shs[c]);
    }
}

// bilinear 2x upsample of concat(x,v0) + skip -> YCAT bf16 NHWC [b][px][384].
// Measured-best config: 64-px tiles, two 192-ch half-passes through 25 KB LDS.
// grid (P2/64, B).
__global__ __launch_bounds__(256) void upsample_kernel(
    const float* __restrict__ x, const float* __restrict__ v0,
    const float* __restrict__ skip, short* __restrict__ ycat)
{
    __shared__ int buf[64 * 98];
    const int tid = threadIdx.x;
    const int px = tid & 63, jj = tid >> 6;
    const int px0 = blockIdx.x * 64;
    const int b = blockIdx.y;
    const int pxg = px0 + px;
    const int ox = pxg & 127, oy = pxg >> 7;
    int my = oy >> 1, mx = ox >> 1;
    int iy0 = (oy & 1) ? my : my - 1;
    float wy0 = (oy & 1) ? 0.75f : 0.25f;
    int ix0 = (ox & 1) ? mx : mx - 1;
    float wx0 = (ox & 1) ? 0.75f : 0.25f;
    int iy1 = min(iy0 + 1, H1 - 1); iy0 = max(iy0, 0);
    int ix1 = min(ix0 + 1, W1 - 1); ix0 = max(ix0, 0);
    float wy1 = 1.f - wy0, wx1 = 1.f - wx0;
    float w00 = wy0 * wx0, w01 = wy0 * wx1, w10 = wy1 * wx0, w11 = wy1 * wx1;
    int o00 = iy0 * W1 + ix0, o01 = iy0 * W1 + ix1;
    int o10 = iy1 * W1 + ix0, o11 = iy1 * W1 + ix1;

#pragma unroll
    for (int half = 0; half < 2; half++) {
        if (half == 1) __syncthreads();   // buf writes of prev half consumed
#pragma unroll 4
        for (int ji = 0; ji < 24; ji++) {
            int j = jj + 4 * ji + half * 96;  // global ch-pair 0..191
            int c = 2 * j;
            float a, d;
            if (c < 256) {
                const float* s0 = (c < 128) ? x + ((size_t)(b * NF + c)) * P1
                                            : v0 + ((size_t)(b * NF + c - 128)) * P1;
                const float* s1 = s0 + P1;
                a = w00 * s0[o00] + w01 * s0[o01] + w10 * s0[o10] + w11 * s0[o11];
                d = w00 * s1[o00] + w01 * s1[o01] + w10 * s1[o10] + w11 * s1[o11];
            } else {
                const float* sk = skip + ((size_t)(b * NF + c - 256)) * P2 + pxg;
                a = sk[0]; d = sk[P2];
            }
            buf[px * 98 + (j - half * 96)] = packbf(a, d);
        }
        __syncthreads();
#pragma unroll
        for (int k = 0; k < 6; k++) {
            int idx = tid + 256 * k;          // 1536 int4s: 64 px x 24 int4
            int p2 = idx / 24, w4 = idx % 24;
            int4 v = *(const int4*)&buf[p2 * 98 + w4 * 4];
            *(int4*)(ycat + ((size_t)b * P2 + px0 + p2) * 384 + half * 192 + w4 * 8) = v;
        }
    }
}

// 1x1 conv 384->192: K-SPLIT staging (two 192-ch halves through 25.6 KB LDS),
// fragment-linear weights, triple-buffered prefetch; softplus; S fp32 NCHW +
// Sbf bf16 NHWC + fused channel sums. grid (P2/64, B), block 256.
__global__ __launch_bounds__(256, 4) void conv1x1_mfma(
    const short* __restrict__ ycat, const short* __restrict__ wq,
    const float* __restrict__ bias, float* __restrict__ out,
    short* __restrict__ sbf, float* __restrict__ osum)
{
    __shared__ int smem[64 * 100];  // 64 px x 96 ch-pair ints (pad 100); reused
    short* xs = (short*)smem;       // as transpose buf in epilogue
    const int tid = threadIdx.x;
    const int wave = tid >> 6, lane = tid & 63;
    const int lx = lane & 15, q = lane >> 4;
    const int p0 = blockIdx.x * 64;
    const int b = blockIdx.y;
    const int slice = blockIdx.x & (NSLICE - 1);

    f32x4 acc[3][4];
#pragma unroll
    for (int cg = 0; cg < 3; cg++)
#pragma unroll
        for (int pg = 0; pg < 4; pg++) acc[cg][pg] = (f32x4)(0.f);

    const short* wbase = wq + ((size_t)(wave * 3) * 64 + lane) * 8;
    auto ldw = [&](int it, short8* dst) {
#pragma unroll
        for (int cg = 0; cg < 3; cg++)
            dst[cg] = *(const short8*)(wbase + (size_t)(it * 12 + cg) * 512);
    };
    auto mbody = [&](int itl, const short8* a) {
        short8 bfr[4];
#pragma unroll
        for (int pg = 0; pg < 4; pg++)
            bfr[pg] = *(const short8*)(&xs[(pg * 16 + lx) * 200 + itl * 32 + q * 8]);
#pragma unroll
        for (int pg = 0; pg < 4; pg++)
#pragma unroll
            for (int cg = 0; cg < 3; cg++)
                acc[cg][pg] = __builtin_amdgcn_mfma_f32_16x16x32_bf16(
                    a[cg], bfr[pg], acc[cg][pg], 0, 0, 0);
    };

    const short* yb = ycat + ((size_t)b * P2 + p0) * 384;
#pragma unroll
    for (int half = 0; half < 2; half++) {
        if (half == 1) __syncthreads();   // prev half's reads done
        // ---- stage 192 channels [half*192, +192): 1536 short8-parts ----
#pragma unroll
        for (int k = 0; k < 6; k++) {
            int j = tid + 256 * k;
            int spx = j / 24, spart = j - spx * 24;
            short8 v = *(const short8*)(yb + (size_t)spx * 384 + half * 192 + spart * 8);
            *(short8*)(&xs[spx * 200 + spart * 8]) = v;
        }
        __syncthreads();

        // ---- 6 pipelined MFMA its over this half ----
        short8 aA[3], aB[3], aC[3];
        ldw(half * 6 + 0, aA);
        ldw(half * 6 + 1, aB);
#pragma unroll
        for (int c = 0; c < 6; c += 3) {
            ldw(half * 6 + c + 2, aC);
            mbody(c, aA);
            if (c + 3 < 6) ldw(half * 6 + c + 3, aA);
            mbody(c + 1, aB);
            if (c + 4 < 6) ldw(half * 6 + c + 4, aB);
            mbody(c + 2, aC);
        }
    }
    __syncthreads();   // xs reads done; smem reused as transpose buf

    float s1a[3][4], s2a[3][4];
#pragma unroll
    for (int cg = 0; cg < 3; cg++)
#pragma unroll
        for (int r = 0; r < 4; r++) { s1a[cg][r] = 0.f; s2a[cg][r] = 0.f; }
#pragma unroll
    for (int cg = 0; cg < 3; cg++) {
        int co0 = wave * 48 + cg * 16 + q * 4;
#pragma unroll
        for (int pg = 0; pg < 4; pg++) {
            int pl = pg * 16 + lx;
            float v[4];
#pragma unroll
            for (int r = 0; r < 4; r++) {
                v[r] = softplus_f(acc[cg][pg][r] + bias[co0 + r]);
                out[((size_t)(b * CS + co0 + r)) * P2 + p0 + pl] = v[r];
                s1a[cg][r] += v[r]; s2a[cg][r] += v[r] * v[r];
            }
            smem[pl * 100 + (co0 >> 1)]     = packbf(v[0], v[1]);
            smem[pl * 100 + (co0 >> 1) + 1] = packbf(v[2], v[3]);
        }
    }
    __syncthreads();
#pragma unroll
    for (int k = 0; k < 6; k++) {
        int idx = tid + 256 * k;
        int p2 = idx / 24, w4 = idx % 24;
        int4 v = *(const int4*)&smem[p2 * 100 + w4 * 4];
        *(int4*)(sbf + ((size_t)b * P2 + p0 + p2) * 192 + w4 * 8) = v;
    }
#pragma unroll
    for (int cg = 0; cg < 3; cg++)
#pragma unroll
        for (int r = 0; r < 4; r++) {
            float a1 = s1a[cg][r], a2 = s2a[cg][r];
#pragma unroll
            for (int mask = 1; mask < 16; mask <<= 1) {
                a1 += __shfl_xor(a1, mask);
                a2 += __shfl_xor(a2, mask);
            }
            if (lx == 0) {
                int co = wave * 48 + cg * 16 + q * 4 + r;
                atomicAdd(&osum[(size_t)slice * 1536 + ((size_t)b * CS + co) * 2], a1);
                atomicAdd(&osum[(size_t)slice * 1536 + ((size_t)b * CS + co) * 2 + 1], a2);
            }
        }
}

// T[a] = S_a + ca1*S_b + ca2*Gx ; T[b] = S_b + cb*Gp ; G in bf16 NCHW;
// T bf16 NHWC; fused channel stats (LDS column walk). grid (P2/64, B).
__global__ __launch_bounds__(256) void combine_kernel(
    const float* __restrict__ S, const short* __restrict__ Gx,
    const short* __restrict__ Gp, short* __restrict__ T, float* __restrict__ osum,
    float ca1, float ca2, float cb)
{
    __shared__ int buf[64 * 100];
    const int tid = threadIdx.x;
    const int px = tid & 63, jj = tid >> 6;
    const int px0 = blockIdx.x * 64;
    const int b = blockIdx.y;
    const int pxg = px0 + px;
    const int slice = blockIdx.x & (NSLICE - 1);
#pragma unroll 3
    for (int ji = 0; ji < 12; ji++) {
        int j = jj + 4 * ji;
        int c = 2 * j;
        size_t ia = ((size_t)(b * CS + c)) * P2 + pxg;
        size_t ib = ia + (size_t)CH * P2;
        size_t ig = ((size_t)(b * CH + c)) * P2 + pxg;
        float sa0 = S[ia], sa1 = S[ia + P2];
        float sb0 = S[ib], sb1 = S[ib + P2];
        float gx0 = bf2f(Gx[ig]), gx1 = bf2f(Gx[ig + P2]);
        float gp0 = bf2f(Gp[ig]), gp1 = bf2f(Gp[ig + P2]);
        buf[px * 100 + j]      = packbf(sa0 + ca1 * sb0 + ca2 * gx0,
                                        sa1 + ca1 * sb1 + ca2 * gx1);
        buf[px * 100 + 48 + j] = packbf(sb0 + cb * gp0, sb1 + cb * gp1);
    }
    __syncthreads();
#pragma unroll
    for (int k = 0; k < 6; k++) {
        int idx = tid + 256 * k;
        int p2 = idx / 24, w4 = idx % 24;
        int4 v = *(const int4*)&buf[p2 * 100 + w4 * 4];
        *(int4*)(T + ((size_t)b * P2 + px0 + p2) * 192 + w4 * 8) = v;
    }
    if (tid < 192) {
        int jj2 = tid >> 1, s = tid & 1;
        float s1lo = 0.f, s2lo = 0.f, s1hi = 0.f, s2hi = 0.f;
#pragma unroll 8
        for (int p = s; p < 64; p += 2) {
            int v = buf[p * 100 + jj2];
            float lo = bf2f((short)v), hi = bf2f((short)(v >> 16));
            s1lo += lo; s2lo += lo * lo; s1hi += hi; s2hi += hi * hi;
        }
        s1lo += __shfl_xor(s1lo, 1); s2lo += __shfl_xor(s2lo, 1);
        s1hi += __shfl_xor(s1hi, 1); s2hi += __shfl_xor(s2hi, 1);
        if (s == 0) {
            int c = 2 * jj2;
            float* dst = &osum[(size_t)slice * 1536 + ((size_t)b * CS + c) * 2];
            atomicAdd(dst, s1lo);
            atomicAdd(dst + 1, s2lo);
            atomicAdd(dst + 2, s1hi);
            atomicAdd(dst + 3, s2hi);
        }
    }
}

// S_a += h*S_b + h^2/6*(g1+g2+g3); S_b += h/6*(g1+2g2+2g3+g4); G bf16 NCHW;
// optional Sbf NHWC with fused channel stats when SBF.
template<bool SBF>
__global__ __launch_bounds__(256) void final_kernel(
    float* __restrict__ S, const short* __restrict__ G1, const short* __restrict__ G2,
    const short* __restrict__ G3, const short* __restrict__ G4,
    short* __restrict__ sbf, float* __restrict__ osum)
{
    __shared__ int buf[SBF ? 64 * 100 : 4];
    const int tid = threadIdx.x;
    const int px = tid & 63, jj = tid >> 6;
    const int px0 = blockIdx.x * 64;
    const int b = blockIdx.y;
    const int pxg = px0 + px;
    const int slice = blockIdx.x & (NSLICE - 1);
    const float cA = DTV * DTV / 6.0f, cB = DTV / 6.0f;
#pragma unroll 3
    for (int ji = 0; ji < 12; ji++) {
        int j = jj + 4 * ji;
        int c = 2 * j;
        size_t ia = ((size_t)(b * CS + c)) * P2 + pxg;
        size_t ib = ia + (size_t)CH * P2;
        size_t ig = ((size_t)(b * CH + c)) * P2 + pxg;
        float sa0 = S[ia], sa1 = S[ia + P2];
        float sb0 = S[ib], sb1 = S[ib + P2];
        float g10 = bf2f(G1[ig]), g11 = bf2f(G1[ig + P2]);
        float g20 = bf2f(G2[ig]), g21 = bf2f(G2[ig + P2]);
        float g30 = bf2f(G3[ig]), g31 = bf2f(G3[ig + P2]);
        float g40 = bf2f(G4[ig]), g41 = bf2f(G4[ig + P2]);
        float na0 = sa0 + DTV * sb0 + cA * (g10 + g20 + g30);
        float na1 = sa1 + DTV * sb1 + cA * (g11 + g21 + g31);
        float nb0 = sb0 + cB * (g10 + 2.f * g20 + 2.f * g30 + g40);
        float nb1 = sb1 + cB * (g11 + 2.f * g21 + 2.f * g31 + g41);
        S[ia] = na0; S[ia + P2] = na1;
        S[ib] = nb0; S[ib + P2] = nb1;
        if (SBF) {
            buf[px * 100 + j]      = packbf(na0, na1);
            buf[px * 100 + 48 + j] = packbf(nb0, nb1);
        }
    }
    if (SBF) {
        __syncthreads();
#pragma unroll
        for (int k = 0; k < 6; k++) {
            int idx = tid + 256 * k;
            int p2 = idx / 24, w4 = idx % 24;
            int4 v = *(const int4*)&buf[p2 * 100 + w4 * 4];
            *(int4*)(sbf + ((size_t)b * P2 + px0 + p2) * 192 + w4 * 8) = v;
        }
        if (tid < 192) {
            int jj2 = tid >> 1, s = tid & 1;
            float s1lo = 0.f, s2lo = 0.f, s1hi = 0.f, s2hi = 0.f;
#pragma unroll 8
            for (int p = s; p < 64; p += 2) {
                int v = buf[p * 100 + jj2];
                float lo = bf2f((short)v), hi = bf2f((short)(v >> 16));
                s1lo += lo; s2lo += lo * lo; s1hi += hi; s2hi += hi * hi;
            }
            s1lo += __shfl_xor(s1lo, 1); s2lo += __shfl_xor(s2lo, 1);
            s1hi += __shfl_xor(s1hi, 1); s2hi += __shfl_xor(s2hi, 1);
            if (s == 0) {
                int c = 2 * jj2;
                float* dst = &osum[(size_t)slice * 1536 + ((size_t)b * CS + c) * 2];
                atomicAdd(dst, s1lo);
                atomicAdd(dst + 1, s2lo);
                atomicAdd(dst + 2, s1hi);
                atomicAdd(dst + 3, s2hi);
            }
        }
    }
}

extern "C" void kernel_launch(void* const* d_in, const int* in_sizes, int n_in,
                              void* d_out, int out_size, void* d_ws, size_t ws_size,
                              hipStream_t stream) {
    (void)in_sizes; (void)n_in; (void)out_size; (void)ws_size;
    const float* x    = (const float*)d_in[0];
    const float* skip = (const float*)d_in[1];
    const float* iv_w = (const float*)d_in[2];
    const float* iv_b = (const float*)d_in[3];
    const float* up_w = (const float*)d_in[4];
    const float* up_b = (const float*)d_in[5];
    const float* f1_w = (const float*)d_in[6];
    const float* f1_b = (const float*)d_in[7];
    const float* f2_w = (const float*)d_in[8];
    const float* f2_b = (const float*)d_in[9];

    float* S = (float*)d_out;                    // B x 192 x P2 fp32 NCHW (state)
    float* ws = (float*)d_ws;
    const size_t NGf = (size_t)BB * CH * P2;
    // G regions keep fp32-sized footprints (addresses unchanged); bf16 data
    // occupies the first half of each. Aliases V0/XBF/YCAT unaffected.
    float* G1f = ws;
    float* G2f = G1f + NGf;
    float* G3f = G2f + NGf;
    float* G4f = G3f + NGf;
    short* GB[4] = {(short*)G1f, (short*)G2f, (short*)G3f, (short*)G4f};
    short* T   = (short*)(G4f + NGf);            // bf16 NHWC [b][P2][192]
    short* U   = T + (size_t)BB * P2 * CS;       // bf16 NHWC [b][P2][96]
    short* SBF = U + (size_t)BB * P2 * CH;       // bf16 NHWC [b][P2][192]
    float* MVS = (float*)(SBF + (size_t)BB * P2 * CS);
    short* IVQ = (short*)(MVS + (size_t)34 * SLOTSZ);
    short* F1Q = IVQ + (size_t)9 * NF * NF;
    short* F2Q = F1Q + (size_t)9 * CH * CS;
    short* UPQ = F2Q + (size_t)9 * CH * CH;
    short* YCAT = (short*)G1f;                   // phase-A alias
    float* V0   = G3f;                           // phase-A alias
    short* XBF  = (short*)G4f;                   // phase-A alias

    auto slot = [&](int i) { return MVS + (size_t)i * SLOTSZ; };

    zero_kernel<<<(34 * SLOTSZ + 255) / 256, 256, 0, stream>>>(MVS, 34 * SLOTSZ);
    repack_w_kernel<<<(NF * NF * 9 + 255) / 256, 256, 0, stream>>>(iv_w, IVQ, NF, NF);
    repack_w_kernel<<<(CH * CS * 9 + 255) / 256, 256, 0, stream>>>(f1_w, F1Q, CH, CS);
    repack_w_kernel<<<(CH * CH * 9 + 255) / 256, 256, 0, stream>>>(f2_w, F2Q, CH, CH);
    repack_w1_kernel<<<(CS * 384 + 255) / 256, 256, 0, stream>>>(up_w, UPQ, CS, 384);

    // ---- Phase A ----
    meanvar_raw_kernel<<<BB * NF, 256, 0, stream>>>(x, slot(0), P1);
    xcvt_kernel<<<dim3(P1 / 64, BB), 256, 0, stream>>>(x, XBF);
    conv3x3_mfma<128, 4, false, false, false><<<dim3(W1 / 16, H1 / 8, BB * 2), 256, 0, stream>>>(
        XBF, slot(0), IVQ, iv_b, V0, nullptr, nullptr, NF, H1, W1, NF, 0, 2);
    upsample_kernel<<<dim3(P2 / 64, BB), 256, 0, stream>>>(x, V0, skip, YCAT);
    conv1x1_mfma<<<dim3(P2 / 64, BB), 256, 0, stream>>>(YCAT, UPQ, up_b, S, SBF, slot(1));

    // ---- RK4 ODE ----
    const float h = DTV;
    int sc = 2;
    float* yslot = slot(1);
    const dim3 egrd(P2 / 64, BB);

    for (int step = 0; step < 4; step++) {
        for (int sub = 0; sub < 4; sub++) {
            const short* Ybf = (sub == 0) ? SBF : T;
            float* uslot = slot(sc++);
            conv3x3_mfma<192, 6, true, false, true><<<dim3(W2 / 16, H2 / 8, BB), 256, 0, stream>>>(
                Ybf, yslot, F1Q, f1_b, nullptr, U, uslot, CH, H2, W2, CH, 0, 1);
            conv3x3_mfma<96, 6, false, true, false><<<dim3(W2 / 16, H2 / 8, BB), 256, 0, stream>>>(
                U, uslot, F2Q, f2_b, nullptr, GB[sub], nullptr, CH, H2, W2, CH, 0, 1);
            if (sub < 3) {
                float ca1, ca2, cb;
                const short *Gx, *Gp;
                if (sub == 0)      { ca1 = h/2; ca2 = 0.f;     Gx = GB[0]; Gp = GB[0]; cb = h/2; }
                else if (sub == 1) { ca1 = h/2; ca2 = h*h/4;   Gx = GB[0]; Gp = GB[1]; cb = h/2; }
                else               { ca1 = h;   ca2 = h*h/2;   Gx = GB[1]; Gp = GB[2]; cb = h;   }
                float* tslot = slot(sc++);
                combine_kernel<<<egrd, 256, 0, stream>>>(S, Gx, Gp, T, tslot, ca1, ca2, cb);
                yslot = tslot;
            }
        }
        if (step < 3) {
            float* sslot = slot(sc++);
            final_kernel<true><<<egrd, 256, 0, stream>>>(S, GB[0], GB[1], GB[2], GB[3], SBF, sslot);
            yslot = sslot;
        } else {
            final_kernel<false><<<egrd, 256, 0, stream>>>(S, GB[0], GB[1], GB[2], GB[3], SBF, nullptr);
        }
    }
}

// Round 16
// 1428.853 us; speedup vs baseline: 1.0907x; 1.0907x over previous
//
#include <hip/hip_runtime.h>
#include <math.h>

#define BB 4
#define NF 128
#define CS 192
#define CH 96
#define H1 64
#define W1 64
#define H2 128
#define W2 128
#define P1 (H1*W1)
#define P2 (H2*W2)
#define EPSV 1e-5f
#define DTV 0.25f
#define NSLICE 32
#define SLOTSZ (1536 * NSLICE)

typedef __attribute__((ext_vector_type(8))) short short8;
typedef __attribute__((ext_vector_type(4))) float f32x4;

__device__ __forceinline__ float softplus_f(float x) {
    return fmaxf(x, 0.0f) + __logf(1.0f + __expf(-fabsf(x)));
}
__device__ __forceinline__ unsigned f2bf(float f) {
    unsigned u = __float_as_uint(f);
    return (u + 0x7FFFu + ((u >> 16) & 1u)) >> 16;   // RNE to bf16
}
__device__ __forceinline__ float bf2f(short s) {
    return __uint_as_float(((unsigned)(unsigned short)s) << 16);
}
__device__ __forceinline__ int packbf(float a, float b) {
    return (int)(f2bf(a) | (f2bf(b) << 16));
}

__global__ __launch_bounds__(256) void zero_kernel(float* __restrict__ p, int n) {
    int i = blockIdx.x * 256 + threadIdx.x;
    if (i < n) p[i] = 0.f;
}

// per-(b,c) raw (sum,sumsq) over HW for fp32 NCHW input x. grid = B*C.
__global__ __launch_bounds__(256) void meanvar_raw_kernel(const float* __restrict__ x,
                                                          float* __restrict__ mv, int HW) {
    int bc = blockIdx.x;
    const float* p = x + (size_t)bc * HW;
    float s = 0.f, s2 = 0.f;
    for (int i = threadIdx.x; i < HW; i += 256) {
        float v = p[i];
        s += v; s2 += v * v;
    }
    __shared__ float sh[512];
    sh[threadIdx.x] = s; sh[256 + threadIdx.x] = s2;
    __syncthreads();
    for (int o = 128; o > 0; o >>= 1) {
        if (threadIdx.x < o) {
            sh[threadIdx.x] += sh[threadIdx.x + o];
            sh[256 + threadIdx.x] += sh[256 + threadIdx.x + o];
        }
        __syncthreads();
    }
    if (threadIdx.x == 0) {
        mv[2 * bc]     = sh[0];
        mv[2 * bc + 1] = sh[256];
    }
}

// repack w[co][ci][3][3] fp32 -> MFMA-fragment-linear bf16, CHUNK-CONTIGUOUS:
// chunk c = it*9 + tap (the conv loop order); WQF[(c*COG + cog)*64 + lane][8],
// lane = q*16 + lx, holding w[co = cog*16+lx][ci = it*32 + q*8 + e].
__global__ __launch_bounds__(256) void repack_w_kernel(const float* __restrict__ w,
                                                       short* __restrict__ wq,
                                                       int Cout, int Cin) {
    int idx = blockIdx.x * 256 + threadIdx.x;
    int total = Cout * Cin * 9;
    if (idx >= total) return;
    int tap = idx % 9;
    int t = idx / 9;
    int ci = t % Cin, co = t / Cin;
    int COGl = Cout >> 4;
    int cog = co >> 4, lx = co & 15;
    int it = ci >> 5, q = (ci >> 3) & 3, e = ci & 7;
    size_t o = (((size_t)(it * 9 + tap) * COGl + cog) * 64 + q * 16 + lx) * 8 + e;
    wq[o] = (short)f2bf(w[idx]);
}

// repack 1x1 w[co][ci] fp32 -> fragment-linear bf16.
__global__ __launch_bounds__(256) void repack_w1_kernel(const float* __restrict__ w,
                                                        short* __restrict__ wq,
                                                        int Cout, int Cin) {
    int idx = blockIdx.x * 256 + threadIdx.x;
    if (idx >= Cout * Cin) return;
    int ci = idx % Cin, co = idx / Cin;
    int COGl = Cout >> 4;
    int cog = co >> 4, lx = co & 15;
    int it = ci >> 5, q = (ci >> 3) & 3, e = ci & 7;
    size_t o = (((size_t)it * COGl + cog) * 64 + q * 16 + lx) * 8 + e;
    wq[o] = (short)f2bf(w[idx]);
}

// x fp32 NCHW (B,128,P1) -> bf16 NHWC [b][px][128], LDS transpose. grid (P1/64, B).
__global__ __launch_bounds__(256) void xcvt_kernel(const float* __restrict__ x,
                                                   short* __restrict__ xbf) {
    __shared__ int buf[64 * 68];
    const int tid = threadIdx.x;
    const int px = tid & 63, jj = tid >> 6;
    const int px0 = blockIdx.x * 64;
    const int b = blockIdx.y;
#pragma unroll
    for (int ji = 0; ji < 16; ji++) {
        int j = jj + 4 * ji;
        int c = 2 * j;
        float a = x[((size_t)(b * NF + c)) * P1 + px0 + px];
        float d = x[((size_t)(b * NF + c + 1)) * P1 + px0 + px];
        buf[px * 68 + j] = packbf(a, d);
    }
    __syncthreads();
#pragma unroll
    for (int k = 0; k < 4; k++) {
        int idx = tid + 256 * k;
        int p2 = idx >> 4, w4 = idx & 15;
        int4 v = *(const int4*)&buf[p2 * 68 + w4 * 4];
        *(int4*)(xbf + ((size_t)b * P1 + px0 + p2) * NF + w4 * 8) = v;
    }
}

// 3x3 SAME conv: whole input tile staged to LDS once, then a FULLY-UNROLLED
// chunk loop with DUAL triple-buffered prefetch: weights (distance 2, global)
// AND bfr LDS fragments (distance 1) -> ds_read latency hides under the
// previous chunk's 12 MFMAs. Occupancy is grid-capped at 2 blocks/CU, so the
// extra ~48 VGPRs of bfr buffering are free. 256 threads = 4 waves: wave
// (wy,wc) owns 4 rows, co-half wc. grid (W/16, H/8, B*coblk), block 256.
template<int CIN, int NCG, bool OUTBF, bool SUMS>
__global__ __launch_bounds__(256) void conv3x3_mfma(
    const short* __restrict__ in, const float* __restrict__ mvsums,
    const short* __restrict__ wq, const float* __restrict__ bias,
    float* __restrict__ outf, short* __restrict__ outbf, float* __restrict__ osum,
    int CoutT, int H, int W, int outC, int outCoff, int coblk)
{
    constexpr int ROWS = CIN + 8;            // shorts per px row
    constexpr int STGI = 180 * ROWS / 2;     // staging ints
    constexpr int SMEMI = (OUTBF && 128 * 52 > STGI) ? 128 * 52 : STGI;
    constexpr int NCGH = NCG / 2;
    __shared__ int smem[SMEMI];
    short* xt = (short*)smem;
    __shared__ float mvm[CIN], mvr[CIN];
    __shared__ float shs[2 * CH];
    const int tid = threadIdx.x;
    const int w4 = tid >> 6, lane = tid & 63;
    const int wy = w4 & 1, wc = w4 >> 1;
    const int lx = lane & 15, q = lane >> 4;
    const int x0 = blockIdx.x * 16, y0 = blockIdx.y * 8;
    const int b = blockIdx.z / coblk;
    const int co_base = (blockIdx.z % coblk) * (NCG * 16);
    const int slice = (blockIdx.x + (blockIdx.y << 3)) & (NSLICE - 1);
    const int HWp = H * W;
    const short* inb = in + (size_t)b * HWp * CIN;

    const float invHW = 1.0f / (float)HWp;
    for (int c = tid; c < CIN; c += 256) {
        float s = 0.f, s2 = 0.f;
#pragma unroll
        for (int sl = 0; sl < NSLICE; sl++) {
            s  += mvsums[(size_t)sl * 1536 + (b * CIN + c) * 2];
            s2 += mvsums[(size_t)sl * 1536 + (b * CIN + c) * 2 + 1];
        }
        float m  = s * invHW;
        float var = fmaxf(s2 * invHW - m * m, 0.f);
        mvm[c] = m;
        mvr[c] = rsqrtf(var + EPSV);
    }
    if (SUMS) for (int c = tid; c < 2 * CH; c += 256) shs[c] = 0.f;
    __syncthreads();

    // ---- stage the whole normalized tile (one pass, coalesced) ----
    constexpr int PARTS = CIN / 8;
    constexpr int TOT = 180 * PARTS;
    constexpr int NJ = (TOT + 255) / 256;
#pragma unroll
    for (int k = 0; k < NJ; k++) {
        int j = tid + 256 * k;
        if (j < TOT) {
            int px = j / PARTS, part = j - px * PARTS;
            int yy = px / 18, xx = px - yy * 18;
            int gy = y0 + yy - 1, gx = x0 + xx - 1;
            int4 wv = make_int4(0, 0, 0, 0);
            if (gy >= 0 && gy < H && gx >= 0 && gx < W) {
                int cb = part * 8;
                short8 v = *(const short8*)(inb + (size_t)(gy * W + gx) * CIN + cb);
                float4 m0 = *(const float4*)&mvm[cb];
                float4 m1 = *(const float4*)&mvm[cb + 4];
                float4 r0 = *(const float4*)&mvr[cb];
                float4 r1 = *(const float4*)&mvr[cb + 4];
                wv.x = packbf((bf2f(v[0]) - m0.x) * r0.x, (bf2f(v[1]) - m0.y) * r0.y);
                wv.y = packbf((bf2f(v[2]) - m0.z) * r0.z, (bf2f(v[3]) - m0.w) * r0.w);
                wv.z = packbf((bf2f(v[4]) - m1.x) * r1.x, (bf2f(v[5]) - m1.y) * r1.y);
                wv.w = packbf((bf2f(v[6]) - m1.z) * r1.z, (bf2f(v[7]) - m1.w) * r1.w);
            }
            *(int4*)(&xt[px * ROWS + part * 8]) = wv;
        }
    }
    __syncthreads();

    // ---- fully-unrolled dual-pipelined compute ----
    f32x4 acc[4][NCGH];
#pragma unroll
    for (int rr = 0; rr < 4; rr++)
#pragma unroll
        for (int cg = 0; cg < NCGH; cg++) acc[rr][cg] = (f32x4)(0.f);

    constexpr int NIT = CIN / 32;
    constexpr int NC = 9 * NIT;              // NC % 3 == 0 always
    const int COGl = CoutT >> 4;
    const short* wbase = wq + ((size_t)((co_base >> 4) + wc * NCGH) * 64 + lane) * 8;
    const size_t wstep = (size_t)COGl * 512;   // shorts per chunk

    auto ldw = [&](int c, short8* dst) {
#pragma unroll
        for (int cg = 0; cg < NCGH; cg++)
            dst[cg] = *(const short8*)(wbase + (size_t)c * wstep + (size_t)cg * 512);
    };
    auto ldb = [&](int c, short8* dst) {
        const int it = c / 9, tap = c - 9 * (c / 9);
        const int dy = tap / 3, dx = tap - 3 * (tap / 3);
#pragma unroll
        for (int rr = 0; rr < 4; rr++)
            dst[rr] = *(const short8*)(
                &xt[((wy * 4 + rr + dy) * 18 + lx + dx) * ROWS + it * 32 + q * 8]);
    };
    auto fma = [&](const short8* a, const short8* bfr) {
#pragma unroll
        for (int rr = 0; rr < 4; rr++)
#pragma unroll
            for (int cg = 0; cg < NCGH; cg++)
                acc[rr][cg] = __builtin_amdgcn_mfma_f32_16x16x32_bf16(
                    a[cg], bfr[rr], acc[rr][cg], 0, 0, 0);
    };

    short8 aA[NCGH], aB[NCGH], aC[NCGH];
    short8 bA[4], bB[4], bC[4];
    ldw(0, aA);
    ldw(1, aB);
    ldb(0, bA);
#pragma unroll
    for (int c = 0; c < NC; c += 3) {
        if (c + 2 < NC) ldw(c + 2, aC);
        if (c + 1 < NC) ldb(c + 1, bB);
        fma(aA, bA);
        if (c + 3 < NC) ldw(c + 3, aA);
        if (c + 2 < NC) ldb(c + 2, bC);
        if (c + 1 < NC) fma(aB, bB);
        if (c + 4 < NC) ldw(c + 4, aB);
        if (c + 3 < NC) ldb(c + 3, bA);
        if (c + 2 < NC) fma(aC, bC);
    }

    if (OUTBF) __syncthreads();   // xt reads done; smem reused as transpose buf

    float s1l[NCGH][4], s2l[NCGH][4];
    if (SUMS) {
#pragma unroll
        for (int cg = 0; cg < NCGH; cg++)
#pragma unroll
            for (int r = 0; r < 4; r++) { s1l[cg][r] = 0.f; s2l[cg][r] = 0.f; }
    }
#pragma unroll
    for (int rr = 0; rr < 4; rr++) {
        int y = y0 + wy * 4 + rr;
#pragma unroll
        for (int cg = 0; cg < NCGH; cg++) {
            float v[4];
#pragma unroll
            for (int r = 0; r < 4; r++) {
                int co = wc * (NCGH * 16) + cg * 16 + q * 4 + r;
                v[r] = softplus_f(acc[rr][cg][r] + bias[co_base + co]);
                if (SUMS) { s1l[cg][r] += v[r]; s2l[cg][r] += v[r] * v[r]; }
            }
            if (OUTBF) {
                int pl = (wy * 4 + rr) * 16 + lx;
                smem[pl * 52 + wc * (NCGH * 8) + cg * 8 + q * 2]     = packbf(v[0], v[1]);
                smem[pl * 52 + wc * (NCGH * 8) + cg * 8 + q * 2 + 1] = packbf(v[2], v[3]);
            } else {
                float* ob = outf + ((size_t)b * outC + outCoff + co_base) * HWp
                            + y * W + x0 + lx;
#pragma unroll
                for (int r = 0; r < 4; r++)
                    ob[(size_t)(wc * (NCGH * 16) + cg * 16 + q * 4 + r) * HWp] = v[r];
            }
        }
    }
    if (OUTBF) {
        __syncthreads();
#pragma unroll
        for (int k = 0; k < 6; k++) {
            int idx = tid + 256 * k;           // 1536 int4s: 128 px x 12 int4
            int pl2 = idx / 12, w4i = idx % 12;
            int4 v = *(const int4*)&smem[pl2 * 52 + w4i * 4];
            int pix = (y0 + (pl2 >> 4)) * W + x0 + (pl2 & 15);
            *(int4*)(outbf + ((size_t)b * HWp + pix) * 96 + w4i * 8) = v;
        }
    }
    if (SUMS) {
#pragma unroll
        for (int cg = 0; cg < NCGH; cg++)
#pragma unroll
            for (int r = 0; r < 4; r++) {
                float a1 = s1l[cg][r], a2 = s2l[cg][r];
#pragma unroll
                for (int mask = 1; mask < 16; mask <<= 1) {
                    a1 += __shfl_xor(a1, mask);
                    a2 += __shfl_xor(a2, mask);
                }
                if (lx == 0) {
                    int co = wc * (NCGH * 16) + cg * 16 + q * 4 + r;
                    atomicAdd(&shs[2 * co], a1);
                    atomicAdd(&shs[2 * co + 1], a2);
                }
            }
        __syncthreads();
        for (int c = tid; c < 2 * NCG * 16; c += 256)
            atomicAdd(&osum[(size_t)slice * 1536 + (size_t)b * 2 * NCG * 16 + c], shs[c]);
    }
}

// bilinear 2x upsample of concat(x,v0) + skip -> YCAT bf16 NHWC [b][px][384].
// Measured-best config: 64-px tiles, two 192-ch half-passes through 25 KB LDS.
// grid (P2/64, B).
__global__ __launch_bounds__(256) void upsample_kernel(
    const float* __restrict__ x, const float* __restrict__ v0,
    const float* __restrict__ skip, short* __restrict__ ycat)
{
    __shared__ int buf[64 * 98];
    const int tid = threadIdx.x;
    const int px = tid & 63, jj = tid >> 6;
    const int px0 = blockIdx.x * 64;
    const int b = blockIdx.y;
    const int pxg = px0 + px;
    const int ox = pxg & 127, oy = pxg >> 7;
    int my = oy >> 1, mx = ox >> 1;
    int iy0 = (oy & 1) ? my : my - 1;
    float wy0 = (oy & 1) ? 0.75f : 0.25f;
    int ix0 = (ox & 1) ? mx : mx - 1;
    float wx0 = (ox & 1) ? 0.75f : 0.25f;
    int iy1 = min(iy0 + 1, H1 - 1); iy0 = max(iy0, 0);
    int ix1 = min(ix0 + 1, W1 - 1); ix0 = max(ix0, 0);
    float wy1 = 1.f - wy0, wx1 = 1.f - wx0;
    float w00 = wy0 * wx0, w01 = wy0 * wx1, w10 = wy1 * wx0, w11 = wy1 * wx1;
    int o00 = iy0 * W1 + ix0, o01 = iy0 * W1 + ix1;
    int o10 = iy1 * W1 + ix0, o11 = iy1 * W1 + ix1;

#pragma unroll
    for (int half = 0; half < 2; half++) {
        if (half == 1) __syncthreads();   // buf writes of prev half consumed
#pragma unroll 4
        for (int ji = 0; ji < 24; ji++) {
            int j = jj + 4 * ji + half * 96;  // global ch-pair 0..191
            int c = 2 * j;
            float a, d;
            if (c < 256) {
                const float* s0 = (c < 128) ? x + ((size_t)(b * NF + c)) * P1
                                            : v0 + ((size_t)(b * NF + c - 128)) * P1;
                const float* s1 = s0 + P1;
                a = w00 * s0[o00] + w01 * s0[o01] + w10 * s0[o10] + w11 * s0[o11];
                d = w00 * s1[o00] + w01 * s1[o01] + w10 * s1[o10] + w11 * s1[o11];
            } else {
                const float* sk = skip + ((size_t)(b * NF + c - 256)) * P2 + pxg;
                a = sk[0]; d = sk[P2];
            }
            buf[px * 98 + (j - half * 96)] = packbf(a, d);
        }
        __syncthreads();
#pragma unroll
        for (int k = 0; k < 6; k++) {
            int idx = tid + 256 * k;          // 1536 int4s: 64 px x 24 int4
            int p2 = idx / 24, w4 = idx % 24;
            int4 v = *(const int4*)&buf[p2 * 98 + w4 * 4];
            *(int4*)(ycat + ((size_t)b * P2 + px0 + p2) * 384 + half * 192 + w4 * 8) = v;
        }
    }
}

// 1x1 conv 384->192: K-SPLIT staging (two 192-ch halves through 25.6 KB LDS),
// fragment-linear weights, triple-buffered prefetch; softplus; S fp32 NCHW +
// Sbf bf16 NHWC + fused channel sums. grid (P2/64, B), block 256.
__global__ __launch_bounds__(256, 4) void conv1x1_mfma(
    const short* __restrict__ ycat, const short* __restrict__ wq,
    const float* __restrict__ bias, float* __restrict__ out,
    short* __restrict__ sbf, float* __restrict__ osum)
{
    __shared__ int smem[64 * 100];  // 64 px x 96 ch-pair ints (pad 100); reused
    short* xs = (short*)smem;       // as transpose buf in epilogue
    const int tid = threadIdx.x;
    const int wave = tid >> 6, lane = tid & 63;
    const int lx = lane & 15, q = lane >> 4;
    const int p0 = blockIdx.x * 64;
    const int b = blockIdx.y;
    const int slice = blockIdx.x & (NSLICE - 1);

    f32x4 acc[3][4];
#pragma unroll
    for (int cg = 0; cg < 3; cg++)
#pragma unroll
        for (int pg = 0; pg < 4; pg++) acc[cg][pg] = (f32x4)(0.f);

    const short* wbase = wq + ((size_t)(wave * 3) * 64 + lane) * 8;
    auto ldw = [&](int it, short8* dst) {
#pragma unroll
        for (int cg = 0; cg < 3; cg++)
            dst[cg] = *(const short8*)(wbase + (size_t)(it * 12 + cg) * 512);
    };
    auto mbody = [&](int itl, const short8* a) {
        short8 bfr[4];
#pragma unroll
        for (int pg = 0; pg < 4; pg++)
            bfr[pg] = *(const short8*)(&xs[(pg * 16 + lx) * 200 + itl * 32 + q * 8]);
#pragma unroll
        for (int pg = 0; pg < 4; pg++)
#pragma unroll
            for (int cg = 0; cg < 3; cg++)
                acc[cg][pg] = __builtin_amdgcn_mfma_f32_16x16x32_bf16(
                    a[cg], bfr[pg], acc[cg][pg], 0, 0, 0);
    };

    const short* yb = ycat + ((size_t)b * P2 + p0) * 384;
#pragma unroll
    for (int half = 0; half < 2; half++) {
        if (half == 1) __syncthreads();   // prev half's reads done
        // ---- stage 192 channels [half*192, +192): 1536 short8-parts ----
#pragma unroll
        for (int k = 0; k < 6; k++) {
            int j = tid + 256 * k;
            int spx = j / 24, spart = j - spx * 24;
            short8 v = *(const short8*)(yb + (size_t)spx * 384 + half * 192 + spart * 8);
            *(short8*)(&xs[spx * 200 + spart * 8]) = v;
        }
        __syncthreads();

        // ---- 6 pipelined MFMA its over this half ----
        short8 aA[3], aB[3], aC[3];
        ldw(half * 6 + 0, aA);
        ldw(half * 6 + 1, aB);
#pragma unroll
        for (int c = 0; c < 6; c += 3) {
            ldw(half * 6 + c + 2, aC);
            mbody(c, aA);
            if (c + 3 < 6) ldw(half * 6 + c + 3, aA);
            mbody(c + 1, aB);
            if (c + 4 < 6) ldw(half * 6 + c + 4, aB);
            mbody(c + 2, aC);
        }
    }
    __syncthreads();   // xs reads done; smem reused as transpose buf

    float s1a[3][4], s2a[3][4];
#pragma unroll
    for (int cg = 0; cg < 3; cg++)
#pragma unroll
        for (int r = 0; r < 4; r++) { s1a[cg][r] = 0.f; s2a[cg][r] = 0.f; }
#pragma unroll
    for (int cg = 0; cg < 3; cg++) {
        int co0 = wave * 48 + cg * 16 + q * 4;
#pragma unroll
        for (int pg = 0; pg < 4; pg++) {
            int pl = pg * 16 + lx;
            float v[4];
#pragma unroll
            for (int r = 0; r < 4; r++) {
                v[r] = softplus_f(acc[cg][pg][r] + bias[co0 + r]);
                out[((size_t)(b * CS + co0 + r)) * P2 + p0 + pl] = v[r];
                s1a[cg][r] += v[r]; s2a[cg][r] += v[r] * v[r];
            }
            smem[pl * 100 + (co0 >> 1)]     = packbf(v[0], v[1]);
            smem[pl * 100 + (co0 >> 1) + 1] = packbf(v[2], v[3]);
        }
    }
    __syncthreads();
#pragma unroll
    for (int k = 0; k < 6; k++) {
        int idx = tid + 256 * k;
        int p2 = idx / 24, w4 = idx % 24;
        int4 v = *(const int4*)&smem[p2 * 100 + w4 * 4];
        *(int4*)(sbf + ((size_t)b * P2 + p0 + p2) * 192 + w4 * 8) = v;
    }
#pragma unroll
    for (int cg = 0; cg < 3; cg++)
#pragma unroll
        for (int r = 0; r < 4; r++) {
            float a1 = s1a[cg][r], a2 = s2a[cg][r];
#pragma unroll
            for (int mask = 1; mask < 16; mask <<= 1) {
                a1 += __shfl_xor(a1, mask);
                a2 += __shfl_xor(a2, mask);
            }
            if (lx == 0) {
                int co = wave * 48 + cg * 16 + q * 4 + r;
                atomicAdd(&osum[(size_t)slice * 1536 + ((size_t)b * CS + co) * 2], a1);
                atomicAdd(&osum[(size_t)slice * 1536 + ((size_t)b * CS + co) * 2 + 1], a2);
            }
        }
}

// T[a] = S_a + ca1*S_b + ca2*Gx ; T[b] = S_b + cb*Gp ; T bf16 NHWC; fused
// channel stats (LDS column walk). grid (P2/64, B).
__global__ __launch_bounds__(256) void combine_kernel(
    const float* __restrict__ S, const float* __restrict__ Gx,
    const float* __restrict__ Gp, short* __restrict__ T, float* __restrict__ osum,
    float ca1, float ca2, float cb)
{
    __shared__ int buf[64 * 100];
    const int tid = threadIdx.x;
    const int px = tid & 63, jj = tid >> 6;
    const int px0 = blockIdx.x * 64;
    const int b = blockIdx.y;
    const int pxg = px0 + px;
    const int slice = blockIdx.x & (NSLICE - 1);
#pragma unroll 3
    for (int ji = 0; ji < 12; ji++) {
        int j = jj + 4 * ji;
        int c = 2 * j;
        size_t ia = ((size_t)(b * CS + c)) * P2 + pxg;
        size_t ib = ia + (size_t)CH * P2;
        size_t ig = ((size_t)(b * CH + c)) * P2 + pxg;
        float sa0 = S[ia], sa1 = S[ia + P2];
        float sb0 = S[ib], sb1 = S[ib + P2];
        float gx0 = Gx[ig], gx1 = Gx[ig + P2];
        float gp0 = Gp[ig], gp1 = Gp[ig + P2];
        buf[px * 100 + j]      = packbf(sa0 + ca1 * sb0 + ca2 * gx0,
                                        sa1 + ca1 * sb1 + ca2 * gx1);
        buf[px * 100 + 48 + j] = packbf(sb0 + cb * gp0, sb1 + cb * gp1);
    }
    __syncthreads();
#pragma unroll
    for (int k = 0; k < 6; k++) {
        int idx = tid + 256 * k;
        int p2 = idx / 24, w4 = idx % 24;
        int4 v = *(const int4*)&buf[p2 * 100 + w4 * 4];
        *(int4*)(T + ((size_t)b * P2 + px0 + p2) * 192 + w4 * 8) = v;
    }
    if (tid < 192) {
        int jj2 = tid >> 1, s = tid & 1;
        float s1lo = 0.f, s2lo = 0.f, s1hi = 0.f, s2hi = 0.f;
#pragma unroll 8
        for (int p = s; p < 64; p += 2) {
            int v = buf[p * 100 + jj2];
            float lo = bf2f((short)v), hi = bf2f((short)(v >> 16));
            s1lo += lo; s2lo += lo * lo; s1hi += hi; s2hi += hi * hi;
        }
        s1lo += __shfl_xor(s1lo, 1); s2lo += __shfl_xor(s2lo, 1);
        s1hi += __shfl_xor(s1hi, 1); s2hi += __shfl_xor(s2hi, 1);
        if (s == 0) {
            int c = 2 * jj2;
            float* dst = &osum[(size_t)slice * 1536 + ((size_t)b * CS + c) * 2];
            atomicAdd(dst, s1lo);
            atomicAdd(dst + 1, s2lo);
            atomicAdd(dst + 2, s1hi);
            atomicAdd(dst + 3, s2hi);
        }
    }
}

// S_a += h*S_b + h^2/6*(g1+g2+g3); S_b += h/6*(g1+2g2+2g3+g4); optional Sbf NHWC
// with fused channel stats (LDS column walk) when SBF.
template<bool SBF>
__global__ __launch_bounds__(256) void final_kernel(
    float* __restrict__ S, const float* __restrict__ G1, const float* __restrict__ G2,
    const float* __restrict__ G3, const float* __restrict__ G4,
    short* __restrict__ sbf, float* __restrict__ osum)
{
    __shared__ int buf[SBF ? 64 * 100 : 4];
    const int tid = threadIdx.x;
    const int px = tid & 63, jj = tid >> 6;
    const int px0 = blockIdx.x * 64;
    const int b = blockIdx.y;
    const int pxg = px0 + px;
    const int slice = blockIdx.x & (NSLICE - 1);
    const float cA = DTV * DTV / 6.0f, cB = DTV / 6.0f;
#pragma unroll 3
    for (int ji = 0; ji < 12; ji++) {
        int j = jj + 4 * ji;
        int c = 2 * j;
        size_t ia = ((size_t)(b * CS + c)) * P2 + pxg;
        size_t ib = ia + (size_t)CH * P2;
        size_t ig = ((size_t)(b * CH + c)) * P2 + pxg;
        float sa0 = S[ia], sa1 = S[ia + P2];
        float sb0 = S[ib], sb1 = S[ib + P2];
        float g10 = G1[ig], g11 = G1[ig + P2];
        float g20 = G2[ig], g21 = G2[ig + P2];
        float g30 = G3[ig], g31 = G3[ig + P2];
        float g40 = G4[ig], g41 = G4[ig + P2];
        float na0 = sa0 + DTV * sb0 + cA * (g10 + g20 + g30);
        float na1 = sa1 + DTV * sb1 + cA * (g11 + g21 + g31);
        float nb0 = sb0 + cB * (g10 + 2.f * g20 + 2.f * g30 + g40);
        float nb1 = sb1 + cB * (g11 + 2.f * g21 + 2.f * g31 + g41);
        S[ia] = na0; S[ia + P2] = na1;
        S[ib] = nb0; S[ib + P2] = nb1;
        if (SBF) {
            buf[px * 100 + j]      = packbf(na0, na1);
            buf[px * 100 + 48 + j] = packbf(nb0, nb1);
        }
    }
    if (SBF) {
        __syncthreads();
#pragma unroll
        for (int k = 0; k < 6; k++) {
            int idx = tid + 256 * k;
            int p2 = idx / 24, w4 = idx % 24;
            int4 v = *(const int4*)&buf[p2 * 100 + w4 * 4];
            *(int4*)(sbf + ((size_t)b * P2 + px0 + p2) * 192 + w4 * 8) = v;
        }
        if (tid < 192) {
            int jj2 = tid >> 1, s = tid & 1;
            float s1lo = 0.f, s2lo = 0.f, s1hi = 0.f, s2hi = 0.f;
#pragma unroll 8
            for (int p = s; p < 64; p += 2) {
                int v = buf[p * 100 + jj2];
                float lo = bf2f((short)v), hi = bf2f((short)(v >> 16));
                s1lo += lo; s2lo += lo * lo; s1hi += hi; s2hi += hi * hi;
            }
            s1lo += __shfl_xor(s1lo, 1); s2lo += __shfl_xor(s2lo, 1);
            s1hi += __shfl_xor(s1hi, 1); s2hi += __shfl_xor(s2hi, 1);
            if (s == 0) {
                int c = 2 * jj2;
                float* dst = &osum[(size_t)slice * 1536 + ((size_t)b * CS + c) * 2];
                atomicAdd(dst, s1lo);
                atomicAdd(dst + 1, s2lo);
                atomicAdd(dst + 2, s1hi);
                atomicAdd(dst + 3, s2hi);
            }
        }
    }
}

extern "C" void kernel_launch(void* const* d_in, const int* in_sizes, int n_in,
                              void* d_out, int out_size, void* d_ws, size_t ws_size,
                              hipStream_t stream) {
    (void)in_sizes; (void)n_in; (void)out_size; (void)ws_size;
    const float* x    = (const float*)d_in[0];
    const float* skip = (const float*)d_in[1];
    const float* iv_w = (const float*)d_in[2];
    const float* iv_b = (const float*)d_in[3];
    const float* up_w = (const float*)d_in[4];
    const float* up_b = (const float*)d_in[5];
    const float* f1_w = (const float*)d_in[6];
    const float* f1_b = (const float*)d_in[7];
    const float* f2_w = (const float*)d_in[8];
    const float* f2_b = (const float*)d_in[9];

    float* S = (float*)d_out;                    // B x 192 x P2 fp32 NCHW (state)
    float* ws = (float*)d_ws;
    const size_t NGf = (size_t)BB * CH * P2;
    float* G1 = ws;
    float* G2 = G1 + NGf;
    float* G3 = G2 + NGf;
    float* G4 = G3 + NGf;
    short* T   = (short*)(G4 + NGf);             // bf16 NHWC [b][P2][192]
    short* U   = T + (size_t)BB * P2 * CS;       // bf16 NHWC [b][P2][96]
    short* SBF = U + (size_t)BB * P2 * CH;       // bf16 NHWC [b][P2][192]
    float* MVS = (float*)(SBF + (size_t)BB * P2 * CS);
    short* IVQ = (short*)(MVS + (size_t)34 * SLOTSZ);
    short* F1Q = IVQ + (size_t)9 * NF * NF;
    short* F2Q = F1Q + (size_t)9 * CH * CS;
    short* UPQ = F2Q + (size_t)9 * CH * CH;
    short* YCAT = (short*)G1;                    // phase-A alias
    float* V0   = G3;                            // phase-A alias
    short* XBF  = (short*)G4;                    // phase-A alias

    auto slot = [&](int i) { return MVS + (size_t)i * SLOTSZ; };

    zero_kernel<<<(34 * SLOTSZ + 255) / 256, 256, 0, stream>>>(MVS, 34 * SLOTSZ);
    repack_w_kernel<<<(NF * NF * 9 + 255) / 256, 256, 0, stream>>>(iv_w, IVQ, NF, NF);
    repack_w_kernel<<<(CH * CS * 9 + 255) / 256, 256, 0, stream>>>(f1_w, F1Q, CH, CS);
    repack_w_kernel<<<(CH * CH * 9 + 255) / 256, 256, 0, stream>>>(f2_w, F2Q, CH, CH);
    repack_w1_kernel<<<(CS * 384 + 255) / 256, 256, 0, stream>>>(up_w, UPQ, CS, 384);

    // ---- Phase A ----
    meanvar_raw_kernel<<<BB * NF, 256, 0, stream>>>(x, slot(0), P1);
    xcvt_kernel<<<dim3(P1 / 64, BB), 256, 0, stream>>>(x, XBF);
    conv3x3_mfma<128, 4, false, false><<<dim3(W1 / 16, H1 / 8, BB * 2), 256, 0, stream>>>(
        XBF, slot(0), IVQ, iv_b, V0, nullptr, nullptr, NF, H1, W1, NF, 0, 2);
    upsample_kernel<<<dim3(P2 / 64, BB), 256, 0, stream>>>(x, V0, skip, YCAT);
    conv1x1_mfma<<<dim3(P2 / 64, BB), 256, 0, stream>>>(YCAT, UPQ, up_b, S, SBF, slot(1));

    // ---- RK4 ODE ----
    const float h = DTV;
    float* G[4] = {G1, G2, G3, G4};
    int sc = 2;
    float* yslot = slot(1);
    const dim3 egrd(P2 / 64, BB);

    for (int step = 0; step < 4; step++) {
        for (int sub = 0; sub < 4; sub++) {
            const short* Ybf = (sub == 0) ? SBF : T;
            float* uslot = slot(sc++);
            conv3x3_mfma<192, 6, true, true><<<dim3(W2 / 16, H2 / 8, BB), 256, 0, stream>>>(
                Ybf, yslot, F1Q, f1_b, nullptr, U, uslot, CH, H2, W2, CH, 0, 1);
            conv3x3_mfma<96, 6, false, false><<<dim3(W2 / 16, H2 / 8, BB), 256, 0, stream>>>(
                U, uslot, F2Q, f2_b, G[sub], nullptr, nullptr, CH, H2, W2, CH, 0, 1);
            if (sub < 3) {
                float ca1, ca2, cb;
                const float *Gx, *Gp;
                if (sub == 0)      { ca1 = h/2; ca2 = 0.f;     Gx = G1; Gp = G1; cb = h/2; }
                else if (sub == 1) { ca1 = h/2; ca2 = h*h/4;   Gx = G1; Gp = G2; cb = h/2; }
                else               { ca1 = h;   ca2 = h*h/2;   Gx = G2; Gp = G3; cb = h;   }
                float* tslot = slot(sc++);
                combine_kernel<<<egrd, 256, 0, stream>>>(S, Gx, Gp, T, tslot, ca1, ca2, cb);
                yslot = tslot;
            }
        }
        if (step < 3) {
            float* sslot = slot(sc++);
            final_kernel<true><<<egrd, 256, 0, stream>>>(S, G1, G2, G3, G4, SBF, sslot);
            yslot = sslot;
        } else {
            final_kernel<false><<<egrd, 256, 0, stream>>>(S, G1, G2, G3, G4, SBF, nullptr);
        }
    }
}